// Round 4
// baseline (109.224 us; speedup 1.0000x reference)
//
#include <hip/hip_runtime.h>
#include <math.h>

#define NB 1024
#define NR 512
#define ND 256
#define XS_STRIDE 260   // multiple of 4 -> row base 16B-aligned for ds_read_b128

typedef float v2f __attribute__((ext_vector_type(2)));
typedef float v4f __attribute__((ext_vector_type(4)));

constexpr float kBETA  = 6.0f;
constexpr float kLOG2E = 1.4426950408889634f;

#if __has_builtin(__builtin_amdgcn_exp2f)
__device__ __forceinline__ float fast_exp2(float x) { return __builtin_amdgcn_exp2f(x); }
#else
__device__ __forceinline__ float fast_exp2(float x) { return exp2f(x); }
#endif
#if __has_builtin(__builtin_amdgcn_rcpf)
__device__ __forceinline__ float fast_rcp(float x) { return __builtin_amdgcn_rcpf(x); }
#else
__device__ __forceinline__ float fast_rcp(float x) { return 1.0f / x; }
#endif

__device__ __forceinline__ float fast_sigmoid(float a) {   // 1/(1+e^-a)
    return fast_rcp(1.0f + fast_exp2(-a * kLOG2E));
}
__device__ __forceinline__ float fast_tanh(float a) {      // 1 - 2/(1+e^{2a})
    return 1.0f - 2.0f * fast_rcp(1.0f + fast_exp2(a * (2.0f * kLOG2E)));
}

// ---- forced packed fp32 (VOP3P). Operand placement keeps <=1 SGPR per op. ----
__device__ __forceinline__ v2f pk_mul_sv(v2f s, v2f v) {           // s may be SGPR pair
    v2f d; asm("v_pk_mul_f32 %0, %1, %2" : "=v"(d) : "s"(s), "v"(v)); return d;
}
__device__ __forceinline__ v2f pk_mul_vv(v2f a, v2f b) {
    v2f d; asm("v_pk_mul_f32 %0, %1, %2" : "=v"(d) : "v"(a), "v"(b)); return d;
}
__device__ __forceinline__ v2f pk_add_sv(v2f s, v2f v) {
    v2f d; asm("v_pk_add_f32 %0, %1, %2" : "=v"(d) : "s"(s), "v"(v)); return d;
}
__device__ __forceinline__ v2f pk_add_vv(v2f a, v2f b) {
    v2f d; asm("v_pk_add_f32 %0, %1, %2" : "=v"(d) : "v"(a), "v"(b)); return d;
}
__device__ __forceinline__ v2f pk_fma_svv(v2f s, v2f b, v2f c) {
    v2f d; asm("v_pk_fma_f32 %0, %1, %2, %3" : "=v"(d) : "s"(s), "v"(b), "v"(c)); return d;
}
__device__ __forceinline__ v2f pk_fma_vvv(v2f a, v2f b, v2f c) {
    v2f d; asm("v_pk_fma_f32 %0, %1, %2, %3" : "=v"(d) : "v"(a), "v"(b), "v"(c)); return d;
}

// Prep: P8[r][pair j] = {E.xy, K.xy, mel.xy, meh.xy}  (32B per d-pair)
//   E = exp2(-s*t_high)  (b = Xe*E with Xe = exp2(s*x): separable exp)
//   K = exp2(-s*width), mel = sig(mask)*tanh(e_low), meh likewise.
__global__ __launch_bounds__(256) void prep_kernel(
    const float* __restrict__ center, const float* __restrict__ log_width,
    const float* __restrict__ e_low, const float* __restrict__ e_high,
    const float* __restrict__ mask, const float* __restrict__ log_kappa,
    const float* __restrict__ head_b,
    float* __restrict__ P8, float* __restrict__ baseR, float* __restrict__ y)
{
    const int r = blockIdx.x;
    const int d = threadIdx.x;
    const int idx = r * ND + d;

    const float kappa = fminf(fmaxf(fast_exp2(log_kappa[0] * kLOG2E), 0.5f), 50.0f);
    const float s = kappa * kLOG2E;

    const float wdt = fminf(fmaxf(fast_exp2(log_width[idx] * kLOG2E), 0.001f), 50.0f);
    const float th  = center[idx] + 0.5f * wdt;
    const float E   = fast_exp2(-s * th);
    const float K   = fmaxf(fast_exp2(-s * wdt), 1e-30f);   // floor: keeps den > 0
    const float m   = fast_sigmoid(mask[idx]);
    const float mel = m * fast_tanh(e_low[idx]);
    const float meh = m * fast_tanh(e_high[idx]);

    float* P = P8 + (size_t)r * 1024 + (d >> 1) * 8 + (d & 1);
    P[0] = E; P[2] = K; P[4] = mel; P[6] = meh;

    float v = mel + meh;
    #pragma unroll
    for (int off = 32; off > 0; off >>= 1) v += __shfl_down(v, off, 64);
    __shared__ float red[4];
    if ((d & 63) == 0) red[d >> 6] = v;
    __syncthreads();
    if (d == 0) baseR[r] = red[0] + red[1] + red[2] + red[3];

    const int gid = blockIdx.x * 256 + threadIdx.x;
    if (gid < NB) y[gid] = head_b[0];
}

// Per d-pair (2 elems): b = Xe*E, u=b+1, v=b+K:
//   acc += (mel*b*u + meh*v)/(u*v);   evidence = baseR - 2*sum
// 8 forced-pk ops + 2 scalar rcp; no exp in the loop.
__device__ __forceinline__ void pairstep(const v2f X, const v2f E, const v2f K,
                                         const v2f mel, const v2f meh,
                                         v2f& acc, const v2f one2)
{
    const v2f b   = pk_mul_sv(E, X);
    const v2f u   = pk_add_vv(b, one2);
    const v2f vv  = pk_add_sv(K, b);
    const v2f tu  = pk_mul_vv(b, u);
    const v2f mv  = pk_mul_sv(meh, vv);
    const v2f num = pk_fma_svv(mel, tu, mv);
    const v2f den = pk_mul_vv(u, vv);
    v2f rd; rd.x = fast_rcp(den.x); rd.y = fast_rcp(den.y);
    acc = pk_fma_vvv(num, rd, acc);
}

// Main: 1024 threads = 16 waves; wave w -> r = blockIdx.y*16 + w; lane = b.
// LDS: Xe = exp2(s*x) tile (64 x 256), ds_read_b128 (2 pairs / read).
__global__ __launch_bounds__(1024, 8) void evid_kernel(
    const float* __restrict__ x, const float* __restrict__ log_kappa,
    const float* __restrict__ t_arr, const float* __restrict__ head_w,
    const float* __restrict__ P8, const float* __restrict__ baseR,
    float* __restrict__ y)
{
    __shared__ float xs[64 * XS_STRIDE];

    const int tid = threadIdx.x;
    const int b0 = blockIdx.x * 64;

    const float kappa = fminf(fmaxf(fast_exp2(log_kappa[0] * kLOG2E), 0.5f), 50.0f);
    const float s = kappa * kLOG2E;

    // Stage Xe = exp2(s*x): coalesced float4 global reads, ds_write_b128.
    const float4* xg = (const float4*)(x + (size_t)b0 * ND);
    #pragma unroll
    for (int k = 0; k < 4; ++k) {
        const int i = tid + k * 1024;       // 4096 float4s
        const float4 vv = xg[i];
        const int bb = i >> 6;
        const int cc = (i & 63) << 2;
        v4f val = { fast_exp2(s * vv.x), fast_exp2(s * vv.y),
                    fast_exp2(s * vv.z), fast_exp2(s * vv.w) };
        *(v4f*)(xs + bb * XS_STRIDE + cc) = val;
    }
    __syncthreads();

    const int lane = tid & 63;
    const int w = tid >> 6;
    const int r = __builtin_amdgcn_readfirstlane(blockIdx.y * 16 + w);

    const v2f* __restrict__ pp = (const v2f*)(P8 + (size_t)r * 1024); // SGPR path
    const v4f* xrow4 = (const v4f*)(xs + lane * XS_STRIDE);

    v2f acc0 = {0.0f, 0.0f}, acc1 = {0.0f, 0.0f};
    const v2f one2 = {1.0f, 1.0f};

    #pragma unroll 4
    for (int t = 0; t < 64; ++t) {          // 2 pairs (4 elems) per iter
        const v4f X4 = xrow4[t];            // ds_read_b128
        const v2f Xa = { X4.x, X4.y };
        const v2f Xb = { X4.z, X4.w };
        const v2f* pb = pp + 8 * t;
        pairstep(Xa, pb[0], pb[1], pb[2], pb[3], acc0, one2);
        pairstep(Xb, pb[4], pb[5], pb[6], pb[7], acc1, one2);
    }

    const float ev = baseR[r] - 2.0f * (acc0.x + acc0.y + acc1.x + acc1.y);
    const float za = (kBETA * kLOG2E) * (t_arr[r] - ev);
    const float z = fast_rcp(1.0f + fast_exp2(za));
    const float zw = z * head_w[r];

    // Block-level reduction over the 16 waves (16 r's), then 1 atomic per lane.
    __syncthreads();
    xs[w * 64 + lane] = zw;
    __syncthreads();
    if (w == 0) {
        float ssum = 0.0f;
        #pragma unroll
        for (int q = 0; q < 16; ++q) ssum += xs[q * 64 + lane];
        atomicAdd(&y[b0 + lane], ssum);
    }
}

extern "C" void kernel_launch(void* const* d_in, const int* in_sizes, int n_in,
                              void* d_out, int out_size, void* d_ws, size_t ws_size,
                              hipStream_t stream) {
    const float* x         = (const float*)d_in[0];
    const float* center    = (const float*)d_in[1];
    const float* log_width = (const float*)d_in[2];
    const float* e_low     = (const float*)d_in[3];
    const float* e_high    = (const float*)d_in[4];
    const float* mask      = (const float*)d_in[5];
    const float* log_kappa = (const float*)d_in[6];
    const float* t_arr     = (const float*)d_in[7];
    const float* head_w    = (const float*)d_in[8];
    const float* head_b    = (const float*)d_in[9];
    float* y = (float*)d_out;

    float* P8    = (float*)d_ws;                                   // 2 MB
    float* baseR = (float*)((char*)d_ws + sizeof(float) * NR * 1024);

    prep_kernel<<<NR, 256, 0, stream>>>(center, log_width, e_low, e_high,
                                        mask, log_kappa, head_b, P8, baseR, y);
    evid_kernel<<<dim3(NB / 64, NR / 16), 1024, 0, stream>>>(x, log_kappa, t_arr,
                                                             head_w, P8, baseR, y);
}